// Round 1
// baseline (346.315 us; speedup 1.0000x reference)
//
#include <hip/hip_runtime.h>
#include <hip/hip_bf16.h>

#define V 50000
#define H 256
#define B 512

typedef __bf16 bf16x8 __attribute__((ext_vector_type(8)));
typedef float f32x4 __attribute__((ext_vector_type(4)));

// ---------------- Kernel A: gather + h0@w_hh.T + GRU cell ----------------
// 128 blocks x 256 threads, 4 batches per block. Thread t owns gate index j=t
// (rows j, 256+j, 512+j of w_hh = r,z,n gates).
__global__ __launch_bounds__(256) void gru_h1_kernel(
    const int* __restrict__ ids, const float* __restrict__ h0,
    const float* __restrict__ w_ih, const float* __restrict__ w_hh,
    const float* __restrict__ b_ih, const float* __restrict__ b_hh,
    float* __restrict__ h1_out, __bf16* __restrict__ h1b)
{
    __shared__ float h0s[4 * 256];
    const int t = threadIdx.x;
    const int b0 = blockIdx.x * 4;

#pragma unroll
    for (int i = 0; i < 4; i++)
        h0s[t + i * 256] = h0[b0 * 256 + t + i * 256];
    __syncthreads();

    const int j = t;
    float ar[4] = {0.f, 0.f, 0.f, 0.f};
    float az[4] = {0.f, 0.f, 0.f, 0.f};
    float an[4] = {0.f, 0.f, 0.f, 0.f};
    const float* __restrict__ wr_p = w_hh + j * H;
    const float* __restrict__ wz_p = w_hh + (H + j) * H;
    const float* __restrict__ wn_p = w_hh + (2 * H + j) * H;

#pragma unroll 4
    for (int k = 0; k < H; k++) {
        float wr = wr_p[k], wz = wz_p[k], wn = wn_p[k];
#pragma unroll
        for (int m = 0; m < 4; m++) {
            float h = h0s[m * 256 + k];
            ar[m] = fmaf(wr, h, ar[m]);
            az[m] = fmaf(wz, h, az[m]);
            an[m] = fmaf(wn, h, an[m]);
        }
    }

    const float bir = b_ih[j], biz = b_ih[H + j], bin = b_ih[2 * H + j];
    const float bhr = b_hh[j], bhz = b_hh[H + j], bhn = b_hh[2 * H + j];

#pragma unroll
    for (int m = 0; m < 4; m++) {
        int id = ids[b0 + m];
        // one_hot @ w_ih.T == column gather of w_ih
        float ir = w_ih[(size_t)j * V + id] + bir;
        float iz = w_ih[(size_t)(H + j) * V + id] + biz;
        float inn = w_ih[(size_t)(2 * H + j) * V + id] + bin;
        float hr = ar[m] + bhr;
        float hz = az[m] + bhz;
        float hn = an[m] + bhn;
        float r = 1.f / (1.f + __expf(-(ir + hr)));
        float z = 1.f / (1.f + __expf(-(iz + hz)));
        float n = tanhf(inn + r * hn);
        float h1 = (1.f - z) * n + z * h0s[m * 256 + j];
        h1_out[(b0 + m) * H + j] = h1;
        h1b[(b0 + m) * H + j] = (__bf16)h1;
    }
}

// ---------------- Kernel B: logits = tanh(h1 @ w_out.T + b_out) ----------
// MFMA 16x16x32 bf16. Block tile: 256 m x 64 n, K=256 fully resident in LDS
// (single barrier, no K-loop sync). 4 waves, each 64x64 (4x4 fragments).
#define BN 64
#define BSTR 264  // 256 + 8 bf16 pad: breaks 512B-stride bank conflict, keeps 16B align

__global__ __launch_bounds__(256, 4) void logit_kernel(
    const __bf16* __restrict__ h1b, const float* __restrict__ w_out,
    const float* __restrict__ b_out, float* __restrict__ out)
{
    __shared__ __bf16 Bs[BN * BSTR];  // [v][k], bf16, padded stride
    const int t = threadIdx.x;
    const int n0 = blockIdx.y * BN;
    const int m_tile = blockIdx.x;

    // Stage w_out tile (64 rows x 256 k) fp32 -> bf16 into LDS, coalesced.
    {
        const int c4 = t & 63;  // float4 column: k = c4*4
        const int v0 = t >> 6;  // 0..3
#pragma unroll
        for (int i = 0; i < 16; i++) {
            int v = v0 + i * 4;
            int n = n0 + v;
            f32x4 g = {0.f, 0.f, 0.f, 0.f};
            if (n < V) g = *(const f32x4*)(w_out + (size_t)n * H + c4 * 4);
            struct alignas(8) BH4 { __bf16 h[4]; } p;
            p.h[0] = (__bf16)g[0];
            p.h[1] = (__bf16)g[1];
            p.h[2] = (__bf16)g[2];
            p.h[3] = (__bf16)g[3];
            *(BH4*)&Bs[v * BSTR + c4 * 4] = p;
        }
    }
    __syncthreads();

    const int lane = t & 63;
    const int wave = t >> 6;
    const int q = lane >> 4;    // quad 0..3
    const int v16 = lane & 15;  // row/col within 16
    const int m_base = m_tile * 256 + wave * 64;

    f32x4 acc[4][4];
#pragma unroll
    for (int i = 0; i < 4; i++)
#pragma unroll
        for (int jj = 0; jj < 4; jj++) acc[i][jj] = (f32x4){0.f, 0.f, 0.f, 0.f};

    // A fragment: lane holds A[m = m_base+i*16+v16][k = ks*32 + q*8 + 0..7]
    const __bf16* a_base = h1b + (m_base + v16) * H + q * 8;

#pragma unroll 2
    for (int ks = 0; ks < 8; ks++) {
        bf16x8 a[4], bfr[4];
#pragma unroll
        for (int i = 0; i < 4; i++)
            a[i] = *(const bf16x8*)(a_base + i * 16 * H + ks * 32);
#pragma unroll
        for (int jj = 0; jj < 4; jj++)
            bfr[jj] = *(const bf16x8*)&Bs[(jj * 16 + v16) * BSTR + ks * 32 + q * 8];
#pragma unroll
        for (int i = 0; i < 4; i++)
#pragma unroll
            for (int jj = 0; jj < 4; jj++)
                acc[i][jj] = __builtin_amdgcn_mfma_f32_16x16x32_bf16(
                    a[i], bfr[jj], acc[i][jj], 0, 0, 0);
    }

    // Epilogue: C/D layout row=(lane>>4)*4+reg, col=lane&15 (verified m89).
    float bo[4];
    int vv[4];
#pragma unroll
    for (int jj = 0; jj < 4; jj++) {
        int v = n0 + jj * 16 + v16;
        vv[jj] = v;
        bo[jj] = (v < V) ? b_out[v] : 0.f;
    }
#pragma unroll
    for (int i = 0; i < 4; i++) {
        int mrow = m_base + i * 16 + q * 4;
#pragma unroll
        for (int jj = 0; jj < 4; jj++) {
            if (vv[jj] < V) {
#pragma unroll
                for (int r = 0; r < 4; r++) {
                    out[(size_t)(mrow + r) * V + vv[jj]] = tanhf(acc[i][jj][r] + bo[jj]);
                }
            }
        }
    }
}

extern "C" void kernel_launch(void* const* d_in, const int* in_sizes, int n_in,
                              void* d_out, int out_size, void* d_ws, size_t ws_size,
                              hipStream_t stream) {
    const int* ids = (const int*)d_in[0];
    const float* hidden = (const float*)d_in[1];  // (1,B,H) -> flat B*H
    const float* w_ih = (const float*)d_in[2];    // (3H, V)
    const float* w_hh = (const float*)d_in[3];    // (3H, H)
    const float* b_ih = (const float*)d_in[4];
    const float* b_hh = (const float*)d_in[5];
    const float* w_out = (const float*)d_in[6];   // (V, H)
    const float* b_out = (const float*)d_in[7];

    float* out = (float*)d_out;                    // logits [B,V]
    float* h1_out = out + (size_t)B * V;           // h1 [1,B,H] tail
    __bf16* h1b = (__bf16*)d_ws;                   // bf16 h1 scratch (256 KB)

    gru_h1_kernel<<<128, 256, 0, stream>>>(ids, hidden, w_ih, w_hh, b_ih, b_hh,
                                           h1_out, h1b);

    dim3 grid(2, (V + BN - 1) / BN);  // m-tiles fastest -> adjacent for L3 reuse
    logit_kernel<<<grid, 256, 0, stream>>>(h1b, w_out, b_out, out);
}

// Round 2
// 333.951 us; speedup vs baseline: 1.0370x; 1.0370x over previous
//
#include <hip/hip_runtime.h>
#include <hip/hip_bf16.h>

#define V 50000
#define H 256
#define B 512

typedef __bf16 bf16x8 __attribute__((ext_vector_type(8)));
typedef float f32x4 __attribute__((ext_vector_type(4)));

__device__ __forceinline__ float tanh_fast(float x) {
    float a = __builtin_fabsf(x);
    float e = __expf(2.0f * a);                       // inf for large a -> r=1
    float r = fmaf(-2.0f, __builtin_amdgcn_rcpf(e + 1.0f), 1.0f);
    return __builtin_copysignf(r, x);
}

// ---------------- Kernel A: gather + h0@w_hh.T + GRU cell ----------------
// 256 blocks x 256 threads, 2 batches per block. Thread t owns gate index j=t.
__global__ __launch_bounds__(256) void gru_h1_kernel(
    const int* __restrict__ ids, const float* __restrict__ h0,
    const float* __restrict__ w_ih, const float* __restrict__ w_hh,
    const float* __restrict__ b_ih, const float* __restrict__ b_hh,
    float* __restrict__ h1_out, __bf16* __restrict__ h1b)
{
    __shared__ float h0s[2 * 256];
    const int t = threadIdx.x;
    const int b0 = blockIdx.x * 2;

#pragma unroll
    for (int i = 0; i < 2; i++)
        h0s[i * 256 + t] = h0[(b0 + i) * 256 + t];
    __syncthreads();

    const int j = t;

    // Issue the scattered one-hot gathers FIRST so their ~900cyc HBM latency
    // overlaps the w_hh dot-product loop.
    int id[2];
    float gir[2], giz[2], gin[2];
#pragma unroll
    for (int m = 0; m < 2; m++) {
        id[m] = ids[b0 + m];
        gir[m] = w_ih[(size_t)j * V + id[m]];
        giz[m] = w_ih[(size_t)(H + j) * V + id[m]];
        gin[m] = w_ih[(size_t)(2 * H + j) * V + id[m]];
    }

    float ar[2] = {0.f, 0.f}, az[2] = {0.f, 0.f}, an[2] = {0.f, 0.f};
    const float* __restrict__ wr_p = w_hh + (size_t)j * H;
    const float* __restrict__ wz_p = w_hh + (size_t)(H + j) * H;
    const float* __restrict__ wn_p = w_hh + (size_t)(2 * H + j) * H;

#pragma unroll 4
    for (int k = 0; k < H; k += 4) {
        f32x4 wr = *(const f32x4*)(wr_p + k);
        f32x4 wz = *(const f32x4*)(wz_p + k);
        f32x4 wn = *(const f32x4*)(wn_p + k);
#pragma unroll
        for (int m = 0; m < 2; m++) {
            f32x4 h = *(const f32x4*)&h0s[m * 256 + k];  // LDS broadcast
#pragma unroll
            for (int u = 0; u < 4; u++) {
                ar[m] = fmaf(wr[u], h[u], ar[m]);
                az[m] = fmaf(wz[u], h[u], az[m]);
                an[m] = fmaf(wn[u], h[u], an[m]);
            }
        }
    }

    const float bir = b_ih[j], biz = b_ih[H + j], bin = b_ih[2 * H + j];
    const float bhr = b_hh[j], bhz = b_hh[H + j], bhn = b_hh[2 * H + j];

#pragma unroll
    for (int m = 0; m < 2; m++) {
        float r = 1.f / (1.f + __expf(-(gir[m] + bir + ar[m] + bhr)));
        float z = 1.f / (1.f + __expf(-(giz[m] + biz + az[m] + bhz)));
        float n = tanh_fast(gin[m] + bin + an[m] + bhn * r + r * an[m] * 0.f
                            + r * (an[m] * 0.f));
        // careful: n-gate is i_n + r*(h_n) with h_n = an + bhn
        n = tanh_fast(gin[m] + bin + r * (an[m] + bhn));
        float h1 = (1.f - z) * n + z * h0s[m * 256 + j];
        h1_out[(b0 + m) * H + j] = h1;
        h1b[(b0 + m) * H + j] = (__bf16)h1;
    }
}

// ---------------- Kernel B: logits = tanh(h1 @ w_out.T + b_out) ----------
// MFMA 16x16x32 bf16, SWAPPED operands: D = Wtile * h1^T, so each lane's 4
// acc regs are 4 CONSECUTIVE n-columns -> dwordx4 stores.
#define BN 64
#define BSTR 264  // 256 + 8 bf16 pad

__global__ __launch_bounds__(256, 4) void logit_kernel(
    const __bf16* __restrict__ h1b, const float* __restrict__ w_out,
    const float* __restrict__ b_out, float* __restrict__ out)
{
    __shared__ __bf16 Bs[BN * BSTR];  // [v][k] bf16, padded stride
    const int t = threadIdx.x;
    const int n0 = blockIdx.x * BN;       // n fastest? no: x = m? see launch
    const int m_tile = blockIdx.y;

    // Stage w_out tile (64 rows x 256 k) fp32 -> bf16 into LDS.
    // Two batches of 8 loads so 8 x 1KB stay in flight per wave.
    {
        const int c4 = t & 63;  // float4 column: k = c4*4
        const int v0 = t >> 6;  // 0..3
#pragma unroll
        for (int half = 0; half < 2; half++) {
            f32x4 g[8];
#pragma unroll
            for (int i = 0; i < 8; i++) {
                int n = n0 + v0 + (half * 8 + i) * 4;
                g[i] = (f32x4){0.f, 0.f, 0.f, 0.f};
                if (n < V) g[i] = *(const f32x4*)(w_out + (size_t)n * H + c4 * 4);
            }
#pragma unroll
            for (int i = 0; i < 8; i++) {
                int v = v0 + (half * 8 + i) * 4;
                struct alignas(8) BH4 { __bf16 h[4]; } p;
                p.h[0] = (__bf16)g[i][0];
                p.h[1] = (__bf16)g[i][1];
                p.h[2] = (__bf16)g[i][2];
                p.h[3] = (__bf16)g[i][3];
                *(BH4*)&Bs[v * BSTR + c4 * 4] = p;
            }
        }
    }
    __syncthreads();

    const int lane = t & 63;
    const int wave = t >> 6;
    const int q = lane >> 4;    // quad 0..3
    const int v16 = lane & 15;
    const int m_base = m_tile * 256 + wave * 64;

    f32x4 acc[4][4];
#pragma unroll
    for (int i = 0; i < 4; i++)
#pragma unroll
        for (int jj = 0; jj < 4; jj++) acc[i][jj] = (f32x4){0.f, 0.f, 0.f, 0.f};

    const __bf16* a_base = h1b + (m_base + v16) * H + q * 8;

#pragma unroll
    for (int ks = 0; ks < 8; ks++) {
        bf16x8 a[4];
#pragma unroll
        for (int i = 0; i < 4; i++)
            a[i] = *(const bf16x8*)(a_base + i * 16 * H + ks * 32);
#pragma unroll
        for (int jj = 0; jj < 4; jj++) {
            bf16x8 bfr = *(const bf16x8*)&Bs[(jj * 16 + v16) * BSTR + ks * 32 + q * 8];
#pragma unroll
            for (int i = 0; i < 4; i++)
                acc[i][jj] = __builtin_amdgcn_mfma_f32_16x16x32_bf16(
                    bfr, a[i], acc[i][jj], 0, 0, 0);  // SWAPPED: D[n][m]
        }
    }

    // Epilogue. Swapped C/D layout: lane holds m = m_base+i*16+v16 (col),
    // n = n0 + jj*16 + q*4 + reg (row). 4 regs = 4 consecutive n -> dwordx4.
#pragma unroll
    for (int jj = 0; jj < 4; jj++) {
        const int n = n0 + jj * 16 + q * 4;
        if (n < V) {  // V%4==0 so all 4 lanes' elems valid together
            f32x4 bo = *(const f32x4*)&b_out[n];
#pragma unroll
            for (int i = 0; i < 4; i++) {
                f32x4 r;
#pragma unroll
                for (int u = 0; u < 4; u++)
                    r[u] = tanh_fast(acc[i][jj][u] + bo[u]);
                *(f32x4*)&out[(size_t)(m_base + i * 16 + v16) * V + n] = r;
            }
        }
    }
}

extern "C" void kernel_launch(void* const* d_in, const int* in_sizes, int n_in,
                              void* d_out, int out_size, void* d_ws, size_t ws_size,
                              hipStream_t stream) {
    const int* ids = (const int*)d_in[0];
    const float* hidden = (const float*)d_in[1];
    const float* w_ih = (const float*)d_in[2];
    const float* w_hh = (const float*)d_in[3];
    const float* b_ih = (const float*)d_in[4];
    const float* b_hh = (const float*)d_in[5];
    const float* w_out = (const float*)d_in[6];
    const float* b_out = (const float*)d_in[7];

    float* out = (float*)d_out;
    float* h1_out = out + (size_t)B * V;
    __bf16* h1b = (__bf16*)d_ws;

    gru_h1_kernel<<<256, 256, 0, stream>>>(ids, hidden, w_ih, w_hh, b_ih, b_hh,
                                           h1_out, h1b);

    dim3 grid((V + BN - 1) / BN, 2);  // x = n-slab, y = m-tile
    logit_kernel<<<grid, 256, 0, stream>>>(h1b, w_out, b_out, out);
}